// Round 4
// baseline (167.596 us; speedup 1.0000x reference)
//
#include <hip/hip_runtime.h>
#include <hip/hip_bf16.h>

// ContrastiveLoss: loss = mean_i [ logsumexp_j(logits[i,:]) - pos_sim[i,i] ]
// logits = [20*xn@tn^T | 20*xn@hn^T + I], rows normalized.
// Round 12: attack the sum-of-pipes, not the schedule.
//  - R8 (serial) / R10 (counted-vmcnt rotation) / R11 (fine phases) all land
//    73-84us @ 15-18% MfmaUtil: scheduling is triple-falsified. Per-MFMA
//    pipe costs ADD on this kernel: ds_read + MFMA + LDS-write + L2-xfer
//    ~19 cyc/MFMA/CU * 8192 MFMA/CU = 64us ~= R8's 73.
//  - Geometry levers: ds_read/MFMA = 1024*(1/acc_r + 1/acc_c) bytes;
//    staged/MFMA = 16384*(BM+BN)/(BM*BN). So: 256x256 tile, 8 waves 2Mx4N,
//    wave = 128x64 out = acc 8x4 -> ds_read 512->384B, staged 256->128B.
//  - Keep R8's PROVEN pieces exactly: 2-barrier __syncthreads loop (~90% of
//    sum-model), 128B-row XOR-swizzled 16B-chunk staging (0 conflicts
//    measured; R11's 64B-row variant conflicted 3.1M cyc - reverted).
//  - scaled-MFMA banned (R2/R4: 252+ regs). b64 LDS reads banned (R5).
//  - logit = acc * (20/127^2); i8 loss error ~1e-3 via diag cancellation.

#define AS1 __attribute__((address_space(1)))
#define AS3 __attribute__((address_space(3)))

constexpr int N = 4096;
constexpr int D = 1024;            // elements per row == bytes per i8 row
constexpr float QSCALE = 127.0f;
constexpr float LSCALE = 20.0f / (127.0f * 127.0f);  // acc -> logit
constexpr float CBIAS = 21.0f;     // >= max possible logit (20*1 + 1)

typedef int i32x4 __attribute__((ext_vector_type(4)));

// 3072 blocks x 256. One row per wave; lane holds 16 CONTIGUOUS floats ->
// 16 int8 bytes -> one uint4 store at byte 16*lane (wave writes 1KB contig).
// Blocks 0..15 also zero rowsum so gemm's atomics start clean.
__global__ __launch_bounds__(256) void normalize_kernel(
    const float* __restrict__ in0, const float* __restrict__ in1,
    const float* __restrict__ in2, unsigned char* __restrict__ Abuf,
    unsigned char* __restrict__ Bbuf, float* __restrict__ rowsum) {
    const int t = threadIdx.x, lane = t & 63, wave = t >> 6;
    if (blockIdx.x < 16) rowsum[blockIdx.x * 256 + t] = 0.f;
    const int row = blockIdx.x * 4 + wave;  // 0..12287
    const int mat = row >> 12, r = row & (N - 1);
    const float* src = (mat == 0) ? in0 : (mat == 1) ? in1 : in2;
    unsigned char* dst = (mat == 0) ? (Abuf + (size_t)r * D)
                       : (mat == 1) ? (Bbuf + (size_t)r * D)
                                    : (Bbuf + (size_t)(r + N) * D);
    const float4* s4 = (const float4*)(src + (size_t)r * D);
    float4 v[4];
    float p = 0.f;
#pragma unroll
    for (int j = 0; j < 4; ++j) {
        v[j] = s4[4 * lane + j];  // floats 16*lane .. 16*lane+15
        p += v[j].x * v[j].x + v[j].y * v[j].y + v[j].z * v[j].z + v[j].w * v[j].w;
    }
#pragma unroll
    for (int m = 1; m < 64; m <<= 1) p += __shfl_xor(p, m);
    const float s = QSCALE / fmaxf(sqrtf(p), 1e-8f);
    uint4 o;
    unsigned int w[4];
#pragma unroll
    for (int j = 0; j < 4; ++j) {
        int q0 = min(127, max(-127, __float2int_rn(v[j].x * s)));
        int q1 = min(127, max(-127, __float2int_rn(v[j].y * s)));
        int q2 = min(127, max(-127, __float2int_rn(v[j].z * s)));
        int q3 = min(127, max(-127, __float2int_rn(v[j].w * s)));
        w[j] = (q0 & 255) | ((q1 & 255) << 8) | ((q2 & 255) << 16)
             | ((unsigned)(q3 & 255) << 24);
    }
    o.x = w[0]; o.y = w[1]; o.z = w[2]; o.w = w[3];
    ((uint4*)dst)[lane] = o;
}

// 256x256 tile, BK=128 i8-bytes, 8 waves (2M x 4N), wave 128x64 out via
// 8x4 of 16x16x64 i8 MFMA per K-half h (2 h per staged tile), b128 reads.
// A:[N,D] i8, B:[2N,D] i8, row-major (frag = 16 contig bytes,
// row = lane&15, k = (lane>>4)*16 + j within the h-half).
// C/D: col = lane&15, row = (lane>>4)*4 + reg (m89-verified, shape-determined).
__global__ __launch_bounds__(512) void gemm_lse_kernel(
    const unsigned char* __restrict__ A, const unsigned char* __restrict__ B,
    float* __restrict__ rowsum, float* __restrict__ posdiag) {
    __shared__ __align__(16) char As[256 * 128];  // 32 KiB
    __shared__ __align__(16) char Bs[256 * 128];  // 32 KiB

    const int tid = threadIdx.x;
    const int lane = tid & 63;
    const int wave = tid >> 6;       // 0..7
    const int wm = wave >> 2;        // 0..1 : 128-row half of A tile
    const int wn = wave & 3;         // 0..3 : 64-col chunk of B tile
    const int quad = lane >> 4, colid = lane & 15;
    const int rowBase = blockIdx.y * 256;
    const int colBase = blockIdx.x * 256;

    i32x4 acc[8][4];
#pragma unroll
    for (int i = 0; i < 8; ++i)
#pragma unroll
        for (int j = 0; j < 4; ++j) acc[i][j] = {0, 0, 0, 0};

    // Staging (R8-proven geometry, 128B rows, 0 conflicts): panel = 2048
    // 16B phys-chunks; thread t fills chunks t + 512j (rows t>>3 + 64j).
    // phys chunk c -> row c>>3, phys col c&7; logical col = (c&7)^(row&7);
    // row&7 == (t>>3)&7 for all j (64j keeps low 3 bits).
    const int srow = tid >> 3;                      // 0..63
    const int scol = (tid & 7) ^ ((tid >> 3) & 7);  // 16B units
    const unsigned char* gA[4];
    const unsigned char* gB[4];
#pragma unroll
    for (int j = 0; j < 4; ++j) {
        gA[j] = A + (size_t)(rowBase + srow + 64 * j) * D + scol * 16;
        gB[j] = B + (size_t)(colBase + srow + 64 * j) * D + scol * 16;
    }

    // Frag offsets: K-half h, row R: logical chunk h*4+quad, phys =
    // (h*4+quad) ^ (R&7); R&7 == colid&7. One b128 IS the MFMA operand.
    int aoff[8][2], boff[4][2];
#pragma unroll
    for (int rt = 0; rt < 8; ++rt) {
        const int R = wm * 128 + rt * 16 + colid;
#pragma unroll
        for (int h = 0; h < 2; ++h)
            aoff[rt][h] = R * 128 + ((h * 4 + quad) ^ (colid & 7)) * 16;
    }
#pragma unroll
    for (int ct = 0; ct < 4; ++ct) {
        const int C = wn * 64 + ct * 16 + colid;
#pragma unroll
        for (int h = 0; h < 2; ++h)
            boff[ct][h] = C * 128 + ((h * 4 + quad) ^ (colid & 7)) * 16;
    }

    for (int kb = 0; kb < D / 128; ++kb) {
        const int k0 = kb * 128;
        __syncthreads();  // prior reads done before overwrite
#pragma unroll
        for (int j = 0; j < 4; ++j) {
            __builtin_amdgcn_global_load_lds((const AS1 void*)(gA[j] + k0),
                (AS3 void*)(As + (tid + 512 * j) * 16), 16, 0, 0);
            __builtin_amdgcn_global_load_lds((const AS1 void*)(gB[j] + k0),
                (AS3 void*)(Bs + (tid + 512 * j) * 16), 16, 0, 0);
        }
        __syncthreads();  // staged data visible

#pragma unroll
        for (int h = 0; h < 2; ++h) {
            i32x4 a[8], b[4];
#pragma unroll
            for (int rt = 0; rt < 8; ++rt)
                a[rt] = *(const i32x4*)(As + aoff[rt][h]);
#pragma unroll
            for (int ct = 0; ct < 4; ++ct)
                b[ct] = *(const i32x4*)(Bs + boff[ct][h]);
            __builtin_amdgcn_s_setprio(1);
#pragma unroll
            for (int rt = 0; rt < 8; ++rt)
#pragma unroll
                for (int ct = 0; ct < 4; ++ct)
                    acc[rt][ct] = __builtin_amdgcn_mfma_i32_16x16x64_i8(
                        a[rt], b[ct], acc[rt][ct], 0, 0, 0);
            __builtin_amdgcn_s_setprio(0);
        }
    }

    // Epilogue: C map col = lane&15, row = quad*4 + reg.
#pragma unroll
    for (int rt = 0; rt < 8; ++rt) {
        float rsum[4] = {0.f, 0.f, 0.f, 0.f};
#pragma unroll
        for (int ct = 0; ct < 4; ++ct) {
#pragma unroll
            for (int reg = 0; reg < 4; ++reg) {
                const int grow = rowBase + wm * 128 + rt * 16 + quad * 4 + reg;
                const int gcol = colBase + wn * 64 + ct * 16 + colid;
                float logit = (float)acc[rt][ct][reg] * LSCALE;
                if (gcol == grow + N) logit += 1.0f;      // hard-negative weight
                if (gcol == grow) posdiag[grow] = logit;  // unique writer
                rsum[reg] += __expf(logit - CBIAS);
            }
        }
#pragma unroll
        for (int reg = 0; reg < 4; ++reg) {
            float v = rsum[reg];
            v += __shfl_xor(v, 1);
            v += __shfl_xor(v, 2);
            v += __shfl_xor(v, 4);
            v += __shfl_xor(v, 8);
            if (colid == 0) {
                const int grow = rowBase + wm * 128 + rt * 16 + quad * 4 + reg;
                atomicAdd(&rowsum[grow], v);
            }
        }
    }
}

__global__ __launch_bounds__(256) void finalize_kernel(
    const float* __restrict__ rowsum, const float* __restrict__ posdiag,
    float* __restrict__ out) {
    const int t = threadIdx.x;
    float s = 0.f;
    for (int i = t; i < N; i += 256)
        s += CBIAS + logf(rowsum[i]) - posdiag[i];
    for (int m = 32; m; m >>= 1) s += __shfl_down(s, m);
    __shared__ float red[4];
    const int lane = t & 63, wave = t >> 6;
    if (lane == 0) red[wave] = s;
    __syncthreads();
    if (t == 0) out[0] = (red[0] + red[1] + red[2] + red[3]) / (float)N;
}

extern "C" void kernel_launch(void* const* d_in, const int* in_sizes, int n_in,
                              void* d_out, int out_size, void* d_ws, size_t ws_size,
                              hipStream_t stream) {
    const float* in0 = (const float*)d_in[0];  // input   [N, D] fp32
    const float* in1 = (const float*)d_in[1];  // target  [N, D] fp32
    const float* in2 = (const float*)d_in[2];  // hardneg [N, D] fp32

    // Workspace: Abuf N*D i8 (4 MiB) | Bbuf 2N*D i8 (8 MiB) | rowsum | posdiag
    unsigned char* Abuf = (unsigned char*)d_ws;
    unsigned char* Bbuf = Abuf + (size_t)N * D;
    float* rowsum = (float*)(Bbuf + (size_t)2 * N * D);
    float* posdiag = rowsum + N;

    normalize_kernel<<<3 * N / 4, 256, 0, stream>>>(in0, in1, in2, Abuf, Bbuf,
                                                    rowsum);
    gemm_lse_kernel<<<dim3(2 * N / 256, N / 256), 512, 0, stream>>>(
        Abuf, Bbuf, rowsum, posdiag);
    finalize_kernel<<<1, 256, 0, stream>>>(rowsum, posdiag, (float*)d_out);
}

// Round 5
// 130.200 us; speedup vs baseline: 1.2872x; 1.2872x over previous
//
#include <hip/hip_runtime.h>
#include <hip/hip_bf16.h>

// ContrastiveLoss: loss = mean_i [ logsumexp_j(logits[i,:]) - pos_sim[i,i] ]
// logits = [20*xn@tn^T | 20*xn@hn^T + I], rows normalized.
// Round 13: TLP, not schedule. R8-R12 (5 schedules/geometries) all 73-84us,
// MfmaUtil 15-18%, occupancy 20-25% (== 2 waves/SIMD, ONE block/CU in
// barrier lockstep). Sum-of-pipes serial model = 44us; measured 77 -> ~32us
// is exposed latency no intra-block schedule removed. The untried lever is
// INTER-block overlap (m114: independent blocks co-schedule MFMA vs stage).
//  - R8 geometry back (128x128, 4 waves, 32KB LDS, proven 0-conflict
//    swizzle) with register diet: LDS frag offsets = 4 base regs +
//    rt*2048 immediates; single staging base ptr per matrix. R8 was
//    72V+64A=136 regs -> 2 waves/SIMD; target <=128 -> 4 waves/SIMD ->
//    4 blocks/CU (launch_bounds(256,4); LDS 4x32KB=128KB fits).
//  - XCD swizzle: flat=(by*64+bx); nf=(flat&7)*256+flat>>3; bx=nf>>5,
//    by=nf&31 -> each XCD: 8 B-col-tiles (1MB) + full A (4MB) ~ L2.
//  - normalize: fully coalesced passes (lane+64j float4 loads, u32 stores).
//  - finalize: 16 blocks, one row/thread, atomicAdd into out (zeroed in
//    normalize; atomic-order noise ~1e-6 << accepted i8 quant error ~1e-3).
//  - scaled-MFMA banned (R2/R4); b64 LDS reads banned (R5); setprio dropped
//    (m190: negative on lockstep GEMM).
//  - logit = acc * (20/127^2); diag cancellation keeps i8 loss error ~1e-3.

#define AS1 __attribute__((address_space(1)))
#define AS3 __attribute__((address_space(3)))

constexpr int N = 4096;
constexpr int D = 1024;            // elements per row == bytes per i8 row
constexpr float QSCALE = 127.0f;
constexpr float LSCALE = 20.0f / (127.0f * 127.0f);  // acc -> logit
constexpr float CBIAS = 21.0f;     // >= max possible logit (20*1 + 1)

typedef int i32x4 __attribute__((ext_vector_type(4)));

// 3072 blocks x 256. One row per wave, 4 coalesced passes: pass j, lane L
// loads float4 #(L+64j) (1KB/inst contiguous) and stores the 4 quantized
// bytes as u32 #(L+64j) (256B/inst contiguous).
// Blocks 0..15 zero rowsum; block 0 zeroes out[0] for finalize's atomics.
__global__ __launch_bounds__(256) void normalize_kernel(
    const float* __restrict__ in0, const float* __restrict__ in1,
    const float* __restrict__ in2, unsigned char* __restrict__ Abuf,
    unsigned char* __restrict__ Bbuf, float* __restrict__ rowsum,
    float* __restrict__ outp) {
    const int t = threadIdx.x, lane = t & 63, wave = t >> 6;
    if (blockIdx.x < 16) rowsum[blockIdx.x * 256 + t] = 0.f;
    if (blockIdx.x == 0 && t == 0) outp[0] = 0.f;
    const int row = blockIdx.x * 4 + wave;  // 0..12287
    const int mat = row >> 12, r = row & (N - 1);
    const float* src = (mat == 0) ? in0 : (mat == 1) ? in1 : in2;
    unsigned char* dst = (mat == 0) ? (Abuf + (size_t)r * D)
                       : (mat == 1) ? (Bbuf + (size_t)r * D)
                                    : (Bbuf + (size_t)(r + N) * D);
    const float4* s4 = (const float4*)(src + (size_t)r * D);
    float4 v[4];
    float p = 0.f;
#pragma unroll
    for (int j = 0; j < 4; ++j) {
        v[j] = s4[lane + 64 * j];  // coalesced: 64 consecutive float4/inst
        p += v[j].x * v[j].x + v[j].y * v[j].y + v[j].z * v[j].z + v[j].w * v[j].w;
    }
#pragma unroll
    for (int m = 1; m < 64; m <<= 1) p += __shfl_xor(p, m);
    const float s = QSCALE / fmaxf(sqrtf(p), 1e-8f);
    unsigned int* d32 = (unsigned int*)dst;
#pragma unroll
    for (int j = 0; j < 4; ++j) {
        int q0 = min(127, max(-127, __float2int_rn(v[j].x * s)));
        int q1 = min(127, max(-127, __float2int_rn(v[j].y * s)));
        int q2 = min(127, max(-127, __float2int_rn(v[j].z * s)));
        int q3 = min(127, max(-127, __float2int_rn(v[j].w * s)));
        d32[lane + 64 * j] = (q0 & 255) | ((q1 & 255) << 8) | ((q2 & 255) << 16)
                           | ((unsigned)(q3 & 255) << 24);
    }
}

// 128x128 tile, BK=128 i8-bytes, 4 waves 2x2, wave 64x64 via 4x4 of
// 16x16x64 i8 MFMA, 2 K-substeps (h) per staged tile, b128 frag reads.
// A:[N,D] i8, B:[2N,D] i8, row-major (frag = 16 contig bytes,
// row = lane&15, k = (lane>>4)*16 + j).
// C/D: col = lane&15, row = (lane>>4)*4 + reg (m89-verified).
// __launch_bounds__(256,4): cap regs at 128 -> 4 blocks/CU for inter-block
// MFMA/stage overlap (the m114 mechanism all prior rounds lacked).
__global__ __launch_bounds__(256, 4) void gemm_lse_kernel(
    const unsigned char* __restrict__ A, const unsigned char* __restrict__ B,
    float* __restrict__ rowsum, float* __restrict__ posdiag) {
    __shared__ __align__(16) char As[128 * 128];  // 16 KiB
    __shared__ __align__(16) char Bs[128 * 128];  // 16 KiB

    const int tid = threadIdx.x;
    const int lane = tid & 63;
    const int wave = tid >> 6;
    const int wr = wave >> 1, wc = wave & 1;
    const int quad = lane >> 4, colid = lane & 15;

    // XCD-aware swizzle (grid 64x32, 2048 blocks, %8==0 -> bijective):
    // XCD x owns bx in [8x,8x+8) for all by -> 1MB B + full 4MB A per L2.
    const int flat = blockIdx.y * 64 + blockIdx.x;
    const int nf = (flat & 7) * 256 + (flat >> 3);
    const int rowBase = (nf & 31) * 128;
    const int colBase = (nf >> 5) * 128;

    i32x4 acc[4][4];
#pragma unroll
    for (int i = 0; i < 4; ++i)
#pragma unroll
        for (int j = 0; j < 4; ++j) acc[i][j] = {0, 0, 0, 0};

    // Staging (R8-proven, 0 conflicts): thread t fills 16B phys-chunks
    // t+256j; phys chunk c -> row c>>3, phys col c&7; logical col =
    // (c&7)^(row&7); row&7 == (t>>3)&7 for all j.
    const int srow = tid >> 3;                      // 0..31
    const int scol = (tid & 7) ^ ((tid >> 3) & 7);  // 16B units
    const unsigned char* gAb = A + (size_t)(rowBase + srow) * D + scol * 16;
    const unsigned char* gBb = B + (size_t)(colBase + srow) * D + scol * 16;

    // Frag offsets, register-dieted: row R = (wr|wc)*64 + rt*16 + colid;
    // R&7 == colid&7; chunk for K-half h = (h*4+quad)^(colid&7).
    // rt/ct stride = 16*128 = 2048 -> folded into ds_read offset imm.
    const int c0 = (quad ^ (colid & 7)) * 16;
    const int c1 = ((4 + quad) ^ (colid & 7)) * 16;
    const int arow = (wr * 64 + colid) * 128;
    const int brow = (wc * 64 + colid) * 128;
    const int aoff0 = arow + c0, aoff1 = arow + c1;
    const int boff0 = brow + c0, boff1 = brow + c1;

    for (int kb = 0; kb < D / 128; ++kb) {
        const int k0 = kb * 128;
        __syncthreads();  // prior reads done before overwrite
        const unsigned char* gA = gAb + k0;  // rows srow+32j at +32768j
        const unsigned char* gB = gBb + k0;
#pragma unroll
        for (int j = 0; j < 4; ++j) {
            __builtin_amdgcn_global_load_lds((const AS1 void*)(gA + 32768 * j),
                (AS3 void*)(As + (tid + 256 * j) * 16), 16, 0, 0);
            __builtin_amdgcn_global_load_lds((const AS1 void*)(gB + 32768 * j),
                (AS3 void*)(Bs + (tid + 256 * j) * 16), 16, 0, 0);
        }
        __syncthreads();  // staged data visible

#pragma unroll
        for (int h = 0; h < 2; ++h) {
            const int ao = h ? aoff1 : aoff0;
            const int bo = h ? boff1 : boff0;
            i32x4 a[4], b[4];
#pragma unroll
            for (int rt = 0; rt < 4; ++rt)
                a[rt] = *(const i32x4*)(As + ao + rt * 2048);
#pragma unroll
            for (int ct = 0; ct < 4; ++ct)
                b[ct] = *(const i32x4*)(Bs + bo + ct * 2048);
#pragma unroll
            for (int rt = 0; rt < 4; ++rt)
#pragma unroll
                for (int ct = 0; ct < 4; ++ct)
                    acc[rt][ct] = __builtin_amdgcn_mfma_i32_16x16x64_i8(
                        a[rt], b[ct], acc[rt][ct], 0, 0, 0);
        }
    }

    // Epilogue: C map col = lane&15, row = quad*4 + reg.
#pragma unroll
    for (int rt = 0; rt < 4; ++rt) {
        float rsum[4] = {0.f, 0.f, 0.f, 0.f};
#pragma unroll
        for (int ct = 0; ct < 4; ++ct) {
#pragma unroll
            for (int reg = 0; reg < 4; ++reg) {
                const int grow = rowBase + wr * 64 + rt * 16 + quad * 4 + reg;
                const int gcol = colBase + wc * 64 + ct * 16 + colid;
                float logit = (float)acc[rt][ct][reg] * LSCALE;
                if (gcol == grow + N) logit += 1.0f;      // hard-negative weight
                if (gcol == grow) posdiag[grow] = logit;  // unique writer
                rsum[reg] += __expf(logit - CBIAS);
            }
        }
#pragma unroll
        for (int reg = 0; reg < 4; ++reg) {
            float v = rsum[reg];
            v += __shfl_xor(v, 1);
            v += __shfl_xor(v, 2);
            v += __shfl_xor(v, 4);
            v += __shfl_xor(v, 8);
            if (colid == 0) {
                const int grow = rowBase + wr * 64 + rt * 16 + quad * 4 + reg;
                atomicAdd(&rowsum[grow], v);
            }
        }
    }
}

// 16 blocks x 256 thr, one row per thread; wave-reduce then one atomic per
// wave into out (out zeroed by normalize earlier in the stream).
__global__ __launch_bounds__(256) void finalize_kernel(
    const float* __restrict__ rowsum, const float* __restrict__ posdiag,
    float* __restrict__ out) {
    const int i = blockIdx.x * 256 + threadIdx.x;
    float s = CBIAS + logf(rowsum[i]) - posdiag[i];
#pragma unroll
    for (int m = 32; m; m >>= 1) s += __shfl_down(s, m);
    if ((threadIdx.x & 63) == 0) atomicAdd(out, s * (1.0f / (float)N));
}

extern "C" void kernel_launch(void* const* d_in, const int* in_sizes, int n_in,
                              void* d_out, int out_size, void* d_ws, size_t ws_size,
                              hipStream_t stream) {
    const float* in0 = (const float*)d_in[0];  // input   [N, D] fp32
    const float* in1 = (const float*)d_in[1];  // target  [N, D] fp32
    const float* in2 = (const float*)d_in[2];  // hardneg [N, D] fp32

    // Workspace: Abuf N*D i8 (4 MiB) | Bbuf 2N*D i8 (8 MiB) | rowsum | posdiag
    unsigned char* Abuf = (unsigned char*)d_ws;
    unsigned char* Bbuf = Abuf + (size_t)N * D;
    float* rowsum = (float*)(Bbuf + (size_t)2 * N * D);
    float* posdiag = rowsum + N;

    normalize_kernel<<<3 * N / 4, 256, 0, stream>>>(in0, in1, in2, Abuf, Bbuf,
                                                    rowsum, (float*)d_out);
    gemm_lse_kernel<<<dim3(2 * N / 128, N / 128), 256, 0, stream>>>(
        Abuf, Bbuf, rowsum, posdiag);
    finalize_kernel<<<16, 256, 0, stream>>>(rowsum, posdiag, (float*)d_out);
}